// Round 1
// baseline (124.014 us; speedup 1.0000x reference)
//
#include <hip/hip_runtime.h>
#include <math.h>

#define HW 128
#define CCH 64
#define EPSF 1.1920929e-7f

typedef unsigned short u16;
typedef __attribute__((ext_vector_type(8))) short bf16x8;
typedef __attribute__((ext_vector_type(4))) float f32x4;

static __device__ __forceinline__ u16 f2bf(float x) {
    unsigned int u = __float_as_uint(x);
    unsigned int r = (u + 0x7FFFu + ((u >> 16) & 1u)) >> 16;   // RNE
    return (u16)r;
}

// ---------------- prep: weight foldpack ONLY (64 blocks) --------------------
// Phase 1 folds the 1x1 conv into 27 virtual-channel weights (9 taps x
// {H,F,validity}) in LDS; phase 2 packs Wp[co][672] bf16.
//   K-enum: k = oct*8 + j; oct<81: t = oct/9, ci = (oct%9)*8 + j
//   ci<64: comp_w lidar half; 64:H 65:F 66:validity(att_b); 67..: 0;
//   oct 81..83 zero-pad (B reads garbage there, zero A kills it).
__global__ void prep_kernel(const float* __restrict__ comp_w,
                            const float* __restrict__ att_w,
                            const float* __restrict__ att_b,
                            u16* __restrict__ Wp) {
    __shared__ float part[27][8];
    __shared__ float W3[27];          // [t*3 + {0:H,1:F,2:validity}]
    int co = blockIdx.x, tid = threadIdx.x;
    // ---- phase 1: 27 dots of length 64, 8-way split
    if (tid < 216) {
        int d = tid >> 3, s = tid & 7;
        int t = d / 3, a = d - t * 3;
        float sum = 0.f;
#pragma unroll
        for (int q = 0; q < 8; ++q) {
            int c2 = s * 8 + q;
            float ww = comp_w[((size_t)co * 128 + 64 + c2) * 9 + t];
            float av = (a == 0) ? att_w[c2 * 2 + 0]
                     : (a == 1) ? att_w[c2 * 2 + 1]
                                : att_b[c2];
            sum = fmaf(ww, av, sum);
        }
        part[d][s] = sum;
    }
    __syncthreads();
    if (tid < 27) {
        float s = 0.f;
#pragma unroll
        for (int q = 0; q < 8; ++q) s += part[tid][q];
        W3[tid] = s;
    }
    __syncthreads();
    // ---- phase 2: pack 672 K-slots for this co
    for (int k = tid; k < 672; k += 256) {
        int oct = k >> 3, j = k & 7;
        u16 v = 0;
        if (oct < 81) {
            int t = oct / 9, o = oct - t * 9;
            int ci = o * 8 + j;
            float w = 0.0f;
            if (ci < 64)      w = comp_w[((size_t)co * 128 + ci) * 9 + t];
            else if (ci < 67) w = W3[t * 3 + (ci - 64)];
            v = f2bf(w);
        }
        Wp[co * 672 + k] = v;
    }
}

// ---------------- MFMA conv with per-tile voxel gather ----------------------
// Phase 0: scan all N voxels, bbox-filter vs this tile's 18x18 halo, compact
//   survivors into LDS (no global atomics, no Hm/Fm round-trip, exact zeros
//   at untouched cells -> no dependence on workspace poison).
// Staging + K-loop + epilogue: identical structure to the verified kernel;
//   only the oct==8 source changed (gather from LDS voxel list instead of
//   reading Hm/Fm from global).
__global__ __launch_bounds__(256)
void conv_kernel(const float* __restrict__ middle,
                 const int* __restrict__ rcoors,
                 const float* __restrict__ rcs,
                 const float* __restrict__ gamma_p,
                 const u16* __restrict__ Wp, const float* __restrict__ comp_b,
                 float* __restrict__ out, int N) {
    const int bx = blockIdx.x, by = blockIdx.y, b = blockIdx.z;
    const int tid = threadIdx.x;
    const int wave = tid >> 6, lane = tid & 63;
    const int col = lane & 15, quad = lane >> 4;
    const int i0 = by * 16 - 1, j0 = bx * 16 - 1;   // halo origin

    __shared__ u16 Xs[18 * 18 * 72];                // 46656 B
    __shared__ int   VP[4096];                      // packed y|x<<8|r<<16
    __shared__ float VI[4096];                      // inv2s2
    __shared__ float VT[4096];                      // true_rcs
    __shared__ int nv;

    if (tid == 0) nv = 0;
    __syncthreads();

    // ---- phase 0: voxel scan + tile bbox filter -> LDS compact list
    {
        float gam = gamma_p[0];
        for (int n = tid; n < N; n += 256) {
            int4 rc = ((const int4*)rcoors)[n];     // (b, _, y, x)
            if (rc.x != b) continue;
            float tr = fmaxf(rcs[n], 0.0f);
            float r = floorf(gam * tr + 1.0f);
            int ri = (int)r;
            int yi = rc.z, xi = rc.w;
            if (yi + ri < i0 || yi - ri > i0 + 17 ||
                xi + ri < j0 || xi - ri > j0 + 17) continue;
            float sigma = (2.0f * r + 1.0f) * (1.0f / 6.0f);
            float inv2s2 = 1.0f / (2.0f * sigma * sigma);
            int slot = atomicAdd(&nv, 1);
            if (slot < 4096) {
                VP[slot] = yi | (xi << 8) | (ri << 16);
                VI[slot] = inv2s2;
                VT[slot] = tr;
            }
        }
    }
    __syncthreads();
    const int nvl = min(nv, 4096);

    // ---- stage halo tile [site][72]: 64 lidar + H + F + ones + 5 zero pad.
    // u = oct*324 + site: a wave holds one channel-octet over 64 consecutive
    // sites -> each inner j-step reads contiguous row-runs (coalesced).
    {
        const float* midB = middle + (size_t)b * CCH * HW * HW;
        for (int u = tid; u < 324 * 9; u += 256) {
            int oct = u / 324, site = u - oct * 324;
            int rr = site / 18, cc = site - rr * 18;
            int gi = i0 + rr, gj = j0 + cc;
            bool in = ((unsigned)gi < HW) && ((unsigned)gj < HW);
            union { u16 h[8]; uint4 v; } pk;
            pk.v = make_uint4(0u, 0u, 0u, 0u);
            if (in) {
                if (oct < 8) {
                    const float* p = midB + (size_t)oct * 8 * HW * HW + gi * HW + gj;
#pragma unroll
                    for (int j = 0; j < 8; ++j)
                        pk.h[j] = f2bf(p[(size_t)j * HW * HW]);
                } else {
                    // gather H/F for this site from the compacted voxel list
                    float Hv = 0.0f, Fv = 0.0f;
                    for (int v = 0; v < nvl; ++v) {
                        int pv = VP[v];                  // LDS broadcast
                        int dy = gi - (pv & 0xFF);
                        int dx = gj - ((pv >> 8) & 0xFF);
                        int ri = pv >> 16;
                        if (abs(dy) > ri || abs(dx) > ri) continue;
                        float g = expf(-(float)(dy * dy + dx * dx) * VI[v]);
                        if (g < EPSF) continue;          // reference: g<eps -> 0
                        Hv = fmaxf(Hv, g);
                        Fv = fmaxf(Fv, g * VT[v]);
                    }
                    pk.h[0] = f2bf(Hv);
                    pk.h[1] = f2bf(Fv);
                    pk.h[2] = 0x3F80u;   // validity plane: bf16 1.0
                }
            }
            *(uint4*)(Xs + site * 72 + oct * 8) = pk.v;
        }
    }
    __syncthreads();

    // ---- K-loop: 21 chunks of 32, mfma 16x16x32 bf16, 4 msubs x 4 nsubs ----
    f32x4 acc[4][4];
#pragma unroll
    for (int m = 0; m < 4; ++m)
#pragma unroll
        for (int n = 0; n < 4; ++n) acc[m][n] = (f32x4){0.f, 0.f, 0.f, 0.f};

#pragma unroll
    for (int c = 0; c < 21; ++c) {
        bf16x8 af[4];
#pragma unroll
        for (int m = 0; m < 4; ++m)
            af[m] = *(const bf16x8*)(Wp + (m * 16 + col) * 672 + c * 32 + quad * 8);

        int oct = c * 4 + quad;
        if (oct > 80) oct = 80;            // A is zero there; any valid B addr ok
        int t  = oct / 9;
        int o  = oct - t * 9;
        int dy = t / 3, dx = t - dy * 3;
        const u16* Bb = Xs + ((wave * 4 + dy) * 18 + (col + dx)) * 72 + o * 8;

        bf16x8 bfr[4];
#pragma unroll
        for (int n = 0; n < 4; ++n)
            bfr[n] = *(const bf16x8*)(Bb + n * (18 * 72));

#pragma unroll
        for (int m = 0; m < 4; ++m)
#pragma unroll
            for (int n = 0; n < 4; ++n)
                acc[m][n] = __builtin_amdgcn_mfma_f32_16x16x32_bf16(af[m], bfr[n], acc[m][n], 0, 0, 0);
    }

    // ---- epilogue: D row = quad*4 + reg (co), D col = pixel x
#pragma unroll
    for (int m = 0; m < 4; ++m) {
        int co0 = m * 16 + quad * 4;
#pragma unroll
        for (int n = 0; n < 4; ++n) {
            int i = by * 16 + wave * 4 + n;
            int j = bx * 16 + col;
            float* o0 = out + (((size_t)(b * 64 + co0) * HW + i) * HW + j);
#pragma unroll
            for (int r = 0; r < 4; ++r)
                o0[(size_t)r * HW * HW] = acc[m][n][r] + comp_b[co0 + r];
        }
    }
}

extern "C" void kernel_launch(void* const* d_in, const int* in_sizes, int n_in,
                              void* d_out, int out_size, void* d_ws, size_t ws_size,
                              hipStream_t stream) {
    const float* middle  = (const float*)d_in[0];
    const int*   rcoors  = (const int*)d_in[2];
    const float* rcs     = (const float*)d_in[4];
    const float* gamma   = (const float*)d_in[5];
    const float* att_w   = (const float*)d_in[6];
    const float* att_b   = (const float*)d_in[7];
    const float* comp_w  = (const float*)d_in[8];
    const float* comp_b  = (const float*)d_in[9];
    float* out = (float*)d_out;

    int B = in_sizes[0] / (CCH * HW * HW);
    int N = in_sizes[4];

    // workspace: only Wp (64*672 bf16) — Hm/Fm scatter maps eliminated
    u16* Wp = (u16*)d_ws;

    prep_kernel<<<dim3(64), 256, 0, stream>>>(comp_w, att_w, att_b, Wp);
    conv_kernel<<<dim3(8, 8, B), 256, 0, stream>>>(middle, rcoors, rcs, gamma,
                                                   Wp, comp_b, out, N);
}